// Round 1
// 4286.493 us; speedup vs baseline: 1.1081x; 1.1081x over previous
//
#include <hip/hip_runtime.h>
#include <hip/hip_fp16.h>

#define BB 128
#define II 64
#define SS 2048
#define HH 128
#define GG 512   // 4*H
#define OO 64

typedef _Float16 f16x2 __attribute__((ext_vector_type(2)));
union F4H { float4 f4; f16x2 h[4]; };

__device__ __forceinline__ f16x2 pack2(float a, float b) {
    f16x2 r; r.x = (_Float16)a; r.y = (_Float16)b; return r;
}

__device__ __forceinline__ float dot2(f16x2 w, f16x2 v, float c) {
#if __has_builtin(__builtin_amdgcn_fdot2)
    return __builtin_amdgcn_fdot2(w, v, c, false);
#else
    return fmaf((float)w.x, (float)v.x, fmaf((float)w.y, (float)v.y, c));
#endif
}

__device__ __forceinline__ float tanh_f(float v) {
    float a = fabsf(v);
    float e = __expf(-2.0f * a);
    float r = (1.0f - e) * __builtin_amdgcn_rcpf(1.0f + e);
    return v < 0.0f ? -r : r;
}

// quad broadcast: every lane gets lane (quad_base + C)'s value. Pure-VALU DPP.
template<int C>
__device__ __forceinline__ float qb(float v) {
    return __int_as_float(__builtin_amdgcn_mov_dpp(
        __float_as_int(v), 0x55 * C, 0xF, 0xF, true));
}
// partner lane ^4 (direction-unambiguous XOR swizzle)
__device__ __forceinline__ float xor4(float v) {
    return __int_as_float(__builtin_amdgcn_ds_swizzle(__float_as_int(v), 0x101F));
}

// One block per batch element, 512 threads.
// Quad-gate layout: thread j owns gate column (j&3)*128 + (j>>2), so the four
// gates {i,f,o,g} of hidden unit u = j>>2 sit in one quad -> gate combination
// and the state update are DPP quad-broadcasts (no LDS, no barrier).
// Barriers per timestep: 2 (was 5). c/cn states live in registers
// (quad-replicated). x double-buffered + prefetched one step ahead.
// Projection pipelined by one step (out[t-1] stored while computing step t).
// amdgpu_waves_per_eu(2) -> 256-VGPR cap (launch_bounds(512,2) gave an
// effective 128 cap in an earlier round -> total spill).
__global__ void __launch_bounds__(512)
__attribute__((amdgpu_waves_per_eu(2)))
nlstm_scan(
    const float* __restrict__ x,
    const float* __restrict__ Wx_out, const float* __restrict__ Wh_out,
    const float* __restrict__ b_out,
    const float* __restrict__ Wx_in, const float* __restrict__ Wh_in,
    const float* __restrict__ b_in,
    const float* __restrict__ W_lin, const float* __restrict__ b_lin,
    float* __restrict__ out)
{
    const int b = blockIdx.x;
    const int j = threadIdx.x;
    const int u = j >> 2;          // hidden unit
    const int g = j & 3;           // gate: 0=i 1=f 2=o 3=g
    const int jcol = g * HH + u;   // column of the 512-wide gate matrices

    // Wx_out fp16, chunk-major: LDS slot keyed by j (lane-consecutive b128
    // reads, measured 0 conflicts), but slot j holds column jcol.
    __shared__ __align__(16) float4 wxf[8 * 512];      // 64 KB
    __shared__ __align__(16) f16x2 xb[2][II / 2];      // x_t fp16, double buf
    __shared__ __align__(16) f16x2 hb[HH / 2];         // h fp16
    __shared__ __align__(16) f16x2 xib[HH / 2];        // x_in fp16
    __shared__ __align__(16) f16x2 hib[HH / 2];        // h_in fp16

    // ---- register-resident fp16 weights (column jcol): 192 regs ----
    f16x2 who[HH / 2];   // Wh_out col jcol
    f16x2 wxi[HH / 2];   // Wx_in  col jcol
    f16x2 whi[HH / 2];   // Wh_in  col jcol
#pragma unroll
    for (int m = 0; m < HH / 2; ++m)
        who[m] = pack2(Wh_out[(2 * m) * GG + jcol], Wh_out[(2 * m + 1) * GG + jcol]);
#pragma unroll
    for (int m = 0; m < HH / 2; ++m)
        wxi[m] = pack2(Wx_in[(2 * m) * GG + jcol], Wx_in[(2 * m + 1) * GG + jcol]);
#pragma unroll
    for (int m = 0; m < HH / 2; ++m)
        whi[m] = pack2(Wh_in[(2 * m) * GG + jcol], Wh_in[(2 * m + 1) * GG + jcol]);

    const float bo  = b_out[jcol];
    const float bi2 = b_in[jcol];
    const int   pn = j >> 3;       // projection output column
    const int   ps = j & 7;        // projection k-slice
    const float bl = b_lin[pn];

    // W_lin -> registers (2 chunks of row pn: k = 16*ps .. 16*ps+16)
    F4H wl[2];
#pragma unroll
    for (int q = 0; q < 2; ++q) {
        const int c = 2 * ps + q;
#pragma unroll
        for (int r = 0; r < 4; ++r)
            wl[q].h[r] = pack2(W_lin[pn * HH + 8 * c + 2 * r],
                               W_lin[pn * HH + 8 * c + 2 * r + 1]);
    }

    // Wx_out column jcol -> LDS slot j, fp16
#pragma unroll
    for (int c = 0; c < 8; ++c) {
        F4H w4;
#pragma unroll
        for (int q = 0; q < 4; ++q)
            w4.h[q] = pack2(Wx_out[(8 * c + 2 * q) * GG + jcol],
                            Wx_out[(8 * c + 2 * q + 1) * GG + jcol]);
        wxf[c * 512 + j] = w4.f4;
    }

    const float* xrow = x + (size_t)b * II * SS;   // x[b,i,t] = xrow[i*SS + t]
    float* orow = out + (size_t)b * SS * OO;

    if (j < II / 2) xb[0][j] = pack2(xrow[(2 * j) * SS], xrow[(2 * j + 1) * SS]);
    if (j < HH / 2) hb[j] = pack2(0.f, 0.f);
    __syncthreads();

    float c_reg = 0.f, cn_reg = 0.f;   // quad-replicated cell states (fp32)

    const float4* hb4 = (const float4*)hb;
    const float4* xi4 = (const float4*)xib;
    const float4* hi4 = (const float4*)hib;
    const bool isT = (g == 3);

#pragma unroll 1
    for (int t = 0; t < SS; ++t) {
        const int cur = t & 1;

        // ---- prefetch x_{t+1} (issued first; written to LDS at end) ----
        float xa = 0.f, xc = 0.f;
        const int tn = (t + 1 < SS) ? t + 1 : t;
        if (j < II / 2) {
            xa = xrow[(2 * j) * SS + tn];
            xc = xrow[(2 * j + 1) * SS + tn];
        }

        // ---- outer gates: col jcol of xt@Wx_out + h@Wh_out + b (4-way ILP) ----
        const float4* xc4 = (const float4*)xb[cur];
        float a0 = 0.f, a1 = 0.f, a2 = 0.f, a3 = 0.f;
#pragma unroll
        for (int c = 0; c < 8; ++c) {
            F4H xu; xu.f4 = xc4[c];
            F4H wu; wu.f4 = wxf[c * 512 + j];
            a0 = dot2(wu.h[0], xu.h[0], a0);
            a1 = dot2(wu.h[1], xu.h[1], a1);
            a2 = dot2(wu.h[2], xu.h[2], a2);
            a3 = dot2(wu.h[3], xu.h[3], a3);
        }
#pragma unroll
        for (int c = 0; c < 16; ++c) {
            F4H hu; hu.f4 = hb4[c];
            a0 = dot2(who[4 * c + 0], hu.h[0], a0);
            a1 = dot2(who[4 * c + 1], hu.h[1], a1);
            a2 = dot2(who[4 * c + 2], hu.h[2], a2);
            a3 = dot2(who[4 * c + 3], hu.h[3], a3);
        }
        float acc = ((a0 + a1) + (a2 + a3)) + bo;

        // unified activation: g<3 sigmoid, g==3 tanh = 2*sigm(2x)-1 (branchless)
        float ap = isT ? 2.f * acc : acc;
        float s  = __builtin_amdgcn_rcpf(1.f + __expf(-ap));
        float av = isT ? fmaf(2.f, s, -1.f) : s;

        // gate combination inside the quad (no LDS, no barrier)
        float vi = qb<0>(av), vf = qb<1>(av), vo = qb<2>(av), vg = qb<3>(av);
        float x_in    = vi * vg;        // i * g
        float h_in    = vf * c_reg;     // f * c
        float o_outer = vo;             // kept for h_new

        // ---- projection of h_{t-1} (pipelined; hb still holds h_{t-1}) ----
        float p0 = 0.f, p1 = 0.f;
        {
            F4H hu0; hu0.f4 = hb4[2 * ps];
            F4H hu1; hu1.f4 = hb4[2 * ps + 1];
            p0 = dot2(wl[0].h[0], hu0.h[0], p0);
            p1 = dot2(wl[0].h[1], hu0.h[1], p1);
            p0 = dot2(wl[0].h[2], hu0.h[2], p0);
            p1 = dot2(wl[0].h[3], hu0.h[3], p1);
            p0 = dot2(wl[1].h[0], hu1.h[0], p0);
            p1 = dot2(wl[1].h[1], hu1.h[1], p1);
            p0 = dot2(wl[1].h[2], hu1.h[2], p0);
            p1 = dot2(wl[1].h[3], hu1.h[3], p1);
        }
        float p = p0 + p1;
        p += __shfl_down(p, 4, 8);
        p += __shfl_down(p, 2, 8);
        p += __shfl_down(p, 1, 8);
        if (ps == 0 && t > 0) orow[(size_t)(t - 1) * OO + pn] = p + bl;

        // write x_in/h_in pairs (lane j and its ^4 partner -> one f16x2)
        float xin_n = xor4(x_in);
        float hin_n = xor4(h_in);
        if ((j & 7) == 0) {
            xib[u >> 1] = pack2(x_in, xin_n);
            hib[u >> 1] = pack2(h_in, hin_n);
        }
        __syncthreads();   // B_a: xib/hib visible; hb readers done before write

        // ---- inner gates: col jcol of x_in@Wx_in + h_in@Wh_in + b ----
        float b0 = 0.f, b1 = 0.f, b2 = 0.f, b3 = 0.f;
#pragma unroll
        for (int c = 0; c < 16; ++c) {
            F4H xu; xu.f4 = xi4[c];
            b0 = dot2(wxi[4 * c + 0], xu.h[0], b0);
            b1 = dot2(wxi[4 * c + 1], xu.h[1], b1);
            b2 = dot2(wxi[4 * c + 2], xu.h[2], b2);
            b3 = dot2(wxi[4 * c + 3], xu.h[3], b3);
        }
#pragma unroll
        for (int c = 0; c < 16; ++c) {
            F4H hu; hu.f4 = hi4[c];
            b0 = dot2(whi[4 * c + 0], hu.h[0], b0);
            b1 = dot2(whi[4 * c + 1], hu.h[1], b1);
            b2 = dot2(whi[4 * c + 2], hu.h[2], b2);
            b3 = dot2(whi[4 * c + 3], hu.h[3], b3);
        }
        float acc2 = ((b0 + b1) + (b2 + b3)) + bi2;

        float ap2 = isT ? 2.f * acc2 : acc2;
        float s2  = __builtin_amdgcn_rcpf(1.f + __expf(-ap2));
        float av2 = isT ? fmaf(2.f, s2, -1.f) : s2;

        // state update inside the quad (no LDS, no barrier)
        float ii = qb<0>(av2), fi = qb<1>(av2), oi = qb<2>(av2), gg = qb<3>(av2);
        float cn_new = fmaf(fi, cn_reg, ii * gg);
        cn_reg = cn_new;
        float c_new = oi * tanh_f(cn_new);
        c_reg = c_new;
        float h_new = o_outer * tanh_f(c_new);

        float hn_n = xor4(h_new);
        if ((j & 7) == 0) hb[u >> 1] = pack2(h_new, hn_n);
        if (j < II / 2) xb[cur ^ 1][j] = pack2(xa, xc);
        __syncthreads();   // B_b: h_t + x_{t+1} visible
    }

    // ---- final projection: out[S-1] from h_{S-1} ----
    {
        float p0 = 0.f, p1 = 0.f;
        F4H hu0; hu0.f4 = hb4[2 * ps];
        F4H hu1; hu1.f4 = hb4[2 * ps + 1];
        p0 = dot2(wl[0].h[0], hu0.h[0], p0);
        p1 = dot2(wl[0].h[1], hu0.h[1], p1);
        p0 = dot2(wl[0].h[2], hu0.h[2], p0);
        p1 = dot2(wl[0].h[3], hu0.h[3], p1);
        p0 = dot2(wl[1].h[0], hu1.h[0], p0);
        p1 = dot2(wl[1].h[1], hu1.h[1], p1);
        p0 = dot2(wl[1].h[2], hu1.h[2], p0);
        p1 = dot2(wl[1].h[3], hu1.h[3], p1);
        float p = p0 + p1;
        p += __shfl_down(p, 4, 8);
        p += __shfl_down(p, 2, 8);
        p += __shfl_down(p, 1, 8);
        if (ps == 0) orow[(size_t)(SS - 1) * OO + pn] = p + bl;
    }
}

extern "C" void kernel_launch(void* const* d_in, const int* in_sizes, int n_in,
                              void* d_out, int out_size, void* d_ws, size_t ws_size,
                              hipStream_t stream) {
    (void)in_sizes; (void)n_in; (void)d_ws; (void)ws_size; (void)out_size;
    const float* x      = (const float*)d_in[0];
    const float* Wx_out = (const float*)d_in[1];
    const float* Wh_out = (const float*)d_in[2];
    const float* b_out  = (const float*)d_in[3];
    const float* Wx_in  = (const float*)d_in[4];
    const float* Wh_in  = (const float*)d_in[5];
    const float* b_in   = (const float*)d_in[6];
    const float* W_lin  = (const float*)d_in[7];
    const float* b_lin  = (const float*)d_in[8];
    float* out = (float*)d_out;

    nlstm_scan<<<dim3(BB), dim3(512), 0, stream>>>(
        x, Wx_out, Wh_out, b_out, Wx_in, Wh_in, b_in, W_lin, b_lin, out);
}

// Round 3
// 4033.623 us; speedup vs baseline: 1.1776x; 1.0627x over previous
//
#include <hip/hip_runtime.h>
#include <hip/hip_fp16.h>

#define BB 128
#define II 64
#define SS 2048
#define HH 128
#define GG 512   // 4*H
#define OO 64

typedef _Float16 f16x2 __attribute__((ext_vector_type(2)));
union F4H { float4 f4; f16x2 h[4]; };

__device__ __forceinline__ f16x2 pack2(float a, float b) {
    f16x2 r; r.x = (_Float16)a; r.y = (_Float16)b; return r;
}

__device__ __forceinline__ float dot2(f16x2 w, f16x2 v, float c) {
#if __has_builtin(__builtin_amdgcn_fdot2)
    return __builtin_amdgcn_fdot2(w, v, c, false);
#else
    return fmaf((float)w.x, (float)v.x, fmaf((float)w.y, (float)v.y, c));
#endif
}

__device__ __forceinline__ float tanh_f(float v) {
    float a = fabsf(v);
    float e = __expf(-2.0f * a);
    float r = (1.0f - e) * __builtin_amdgcn_rcpf(1.0f + e);
    return v < 0.0f ? -r : r;
}

// quad broadcast: every lane gets lane (quad_base + C)'s value. Pure-VALU DPP.
template<int C>
__device__ __forceinline__ float qb(float v) {
    return __int_as_float(__builtin_amdgcn_mov_dpp(
        __float_as_int(v), 0x55 * C, 0xF, 0xF, true));
}
// DPP row rotate-LEFT by N within each 16-lane row: lane i <- lane (i+N)&15.
// Implemented as row_ror:(16-N) since DPP only has rotate-right
// (row_ror:N gives lane i <- lane (i-N)&15 — THAT direction broke R2).
template<int N>
__device__ __forceinline__ float rolN(float v) {
    return __int_as_float(__builtin_amdgcn_mov_dpp(
        __float_as_int(v), 0x120 + (16 - N), 0xF, 0xF, true));
}

// LDS-only barrier: __syncthreads() emits s_waitcnt vmcnt(0) lgkmcnt(0) and
// drains in-flight global loads/stores every step. Only LDS ordering is
// needed across our barriers (hb/xib/hib/xt); x-load consumption is a data
// dependence (compiler inserts its own vmcnt wait at the use).
__device__ __forceinline__ void barrier_lds() {
    asm volatile("s_waitcnt lgkmcnt(0)\n\ts_barrier" ::: "memory");
}

// One block per batch element, 512 threads.
// Quad-gate layout: thread j owns gate column (j&3)*128 + (j>>2); gate
// combination and state update are DPP quad-broadcasts (no LDS/barrier).
// 2 raw (lgkm-only) barriers per step. x staged in 16-step LDS tiles,
// coalesced + double-buffered + prefetched one tile ahead.
// VGPR_Count=128 + weights in AGPRs (unified file; VALU reads AGPR direct).
__global__ void __launch_bounds__(512)
__attribute__((amdgpu_waves_per_eu(2)))
nlstm_scan(
    const float* __restrict__ x,
    const float* __restrict__ Wx_out, const float* __restrict__ Wh_out,
    const float* __restrict__ b_out,
    const float* __restrict__ Wx_in, const float* __restrict__ Wh_in,
    const float* __restrict__ b_in,
    const float* __restrict__ W_lin, const float* __restrict__ b_lin,
    float* __restrict__ out)
{
    const int b = blockIdx.x;
    const int j = threadIdx.x;
    const int u = j >> 2;          // hidden unit
    const int g = j & 3;           // gate: 0=i 1=f 2=o 3=g
    const int jcol = g * HH + u;   // column of the 512-wide gate matrices

    __shared__ __align__(16) float4 wxf[8 * 512];      // Wx_out fp16, 64 KB
    // x tile: 16 timesteps, row = timestep, entry m = (x[2m][t],x[2m+1][t]).
    // Row padded to 36 (16B-aligned rows; write banks (4*tl+m)&31 -> 2-way).
    __shared__ __align__(16) f16x2 xt[2][16][36];      // 4.5 KB
    __shared__ __align__(16) f16x2 hb[HH / 2];         // h fp16
    __shared__ __align__(16) f16x2 xib[HH / 2];        // x_in fp16
    __shared__ __align__(16) f16x2 hib[HH / 2];        // h_in fp16

    // ---- register/AGPR-resident fp16 weights (column jcol) ----
    f16x2 who[HH / 2];   // Wh_out col jcol
    f16x2 wxi[HH / 2];   // Wx_in  col jcol
    f16x2 whi[HH / 2];   // Wh_in  col jcol
#pragma unroll
    for (int m = 0; m < HH / 2; ++m)
        who[m] = pack2(Wh_out[(2 * m) * GG + jcol], Wh_out[(2 * m + 1) * GG + jcol]);
#pragma unroll
    for (int m = 0; m < HH / 2; ++m)
        wxi[m] = pack2(Wx_in[(2 * m) * GG + jcol], Wx_in[(2 * m + 1) * GG + jcol]);
#pragma unroll
    for (int m = 0; m < HH / 2; ++m)
        whi[m] = pack2(Wh_in[(2 * m) * GG + jcol], Wh_in[(2 * m + 1) * GG + jcol]);

    const float bo  = b_out[jcol];
    const float bi2 = b_in[jcol];
    const int   pn = j >> 3;       // projection output column
    const int   ps = j & 7;        // projection k-slice
    const float bl = b_lin[pn];

    // W_lin -> registers (2 chunks of row pn: k = 16*ps .. 16*ps+16)
    F4H wl[2];
#pragma unroll
    for (int q = 0; q < 2; ++q) {
        const int c = 2 * ps + q;
#pragma unroll
        for (int r = 0; r < 4; ++r)
            wl[q].h[r] = pack2(W_lin[pn * HH + 8 * c + 2 * r],
                               W_lin[pn * HH + 8 * c + 2 * r + 1]);
    }

    // Wx_out column jcol -> LDS slot j, fp16 (lane-consecutive b128 reads)
#pragma unroll
    for (int c = 0; c < 8; ++c) {
        F4H w4;
#pragma unroll
        for (int q = 0; q < 4; ++q)
            w4.h[q] = pack2(Wx_out[(8 * c + 2 * q) * GG + jcol],
                            Wx_out[(8 * c + 2 * q + 1) * GG + jcol]);
        wxf[c * 512 + j] = w4.f4;
    }

    const float* xrow = x + (size_t)b * II * SS;   // x[b,i,t] = xrow[i*SS + t]
    float* orow = out + (size_t)b * SS * OO;

    // x tile slot for this thread: entry xm of timestep-row xtl
    const int xm  = j >> 4;    // 0..31
    const int xtl = j & 15;    // 0..15
    const float* xg0 = xrow + (size_t)(2 * xm) * SS + xtl;
    const float* xg1 = xrow + (size_t)(2 * xm + 1) * SS + xtl;

    // tile 0 -> buffer 0
    xt[0][xtl][xm] = pack2(xg0[0], xg1[0]);
    if (j < HH / 2) hb[j] = pack2(0.f, 0.f);
    __syncthreads();   // startup: full sync ok

    float c_reg = 0.f, cn_reg = 0.f;   // quad-replicated cell states (fp32)

    const float4* hb4 = (const float4*)hb;
    const float4* xi4 = (const float4*)xib;
    const float4* hi4 = (const float4*)hib;
    const bool isT = (g == 3);

    float pr0 = 0.f, pr1 = 0.f;        // x-tile prefetch registers

#pragma unroll 1
    for (int t = 0; t < SS; ++t) {
        const int stl = t & 15;        // step's row in the tile
        const int tb  = (t >> 4) & 1;  // current tile buffer

        // ---- prefetch next 16-step x tile (uniform branch, 1/16 steps) ----
        if (stl == 0) {
            const int Tn = (t + 16 < SS) ? t + 16 : t;  // clamp: dead reload
            pr0 = xg0[Tn];
            pr1 = xg1[Tn];
        }

        // ---- outer gates: col jcol of xt@Wx_out + h@Wh_out + b (4-way ILP) ----
        const float4* xc4 = (const float4*)&xt[tb][stl][0];
        float a0 = 0.f, a1 = 0.f, a2 = 0.f, a3 = 0.f;
#pragma unroll
        for (int c = 0; c < 8; ++c) {
            F4H xu; xu.f4 = xc4[c];
            F4H wu; wu.f4 = wxf[c * 512 + j];
            a0 = dot2(wu.h[0], xu.h[0], a0);
            a1 = dot2(wu.h[1], xu.h[1], a1);
            a2 = dot2(wu.h[2], xu.h[2], a2);
            a3 = dot2(wu.h[3], xu.h[3], a3);
        }
#pragma unroll
        for (int c = 0; c < 16; ++c) {
            F4H hu; hu.f4 = hb4[c];
            a0 = dot2(who[4 * c + 0], hu.h[0], a0);
            a1 = dot2(who[4 * c + 1], hu.h[1], a1);
            a2 = dot2(who[4 * c + 2], hu.h[2], a2);
            a3 = dot2(who[4 * c + 3], hu.h[3], a3);
        }
        float acc = ((a0 + a1) + (a2 + a3)) + bo;

        // unified activation: g<3 sigmoid, g==3 tanh = 2*sigm(2x)-1
        float ap = isT ? 2.f * acc : acc;
        float s  = __builtin_amdgcn_rcpf(1.f + __expf(-ap));
        float av = isT ? fmaf(2.f, s, -1.f) : s;

        // gate combination inside the quad (no LDS, no barrier)
        float vi = qb<0>(av), vf = qb<1>(av), vo = qb<2>(av), vg = qb<3>(av);
        float x_in    = vi * vg;        // i * g
        float h_in    = vf * c_reg;     // f * c
        float o_outer = vo;             // kept for h_new

        // ---- projection of h_{t-1} (pipelined; hb still holds h_{t-1}) ----
        float p0 = 0.f, p1 = 0.f;
        {
            F4H hu0; hu0.f4 = hb4[2 * ps];
            F4H hu1; hu1.f4 = hb4[2 * ps + 1];
            p0 = dot2(wl[0].h[0], hu0.h[0], p0);
            p1 = dot2(wl[0].h[1], hu0.h[1], p1);
            p0 = dot2(wl[0].h[2], hu0.h[2], p0);
            p1 = dot2(wl[0].h[3], hu0.h[3], p1);
            p0 = dot2(wl[1].h[0], hu1.h[0], p0);
            p1 = dot2(wl[1].h[1], hu1.h[1], p1);
            p0 = dot2(wl[1].h[2], hu1.h[2], p0);
            p1 = dot2(wl[1].h[3], hu1.h[3], p1);
        }
        float p = p0 + p1;
        p += rolN<4>(p);   // lane i += lane i+4  (ps==0 lanes stay in-group)
        p += rolN<2>(p);
        p += rolN<1>(p);
        if (ps == 0 && t > 0) orow[(size_t)(t - 1) * OO + pn] = p + bl;

        // write x_in/h_in pairs (lane j=8k packs units 2k,2k+1 via DPP rol4)
        float xin_n = rolN<4>(x_in);
        float hin_n = rolN<4>(h_in);
        if ((j & 7) == 0) {
            xib[u >> 1] = pack2(x_in, xin_n);
            hib[u >> 1] = pack2(h_in, hin_n);
        }
        barrier_lds();   // B_a: xib/hib visible; hb readers done before write

        // ---- inner gates: col jcol of x_in@Wx_in + h_in@Wh_in + b ----
        float b0 = 0.f, b1 = 0.f, b2 = 0.f, b3 = 0.f;
#pragma unroll
        for (int c = 0; c < 16; ++c) {
            F4H xu; xu.f4 = xi4[c];
            b0 = dot2(wxi[4 * c + 0], xu.h[0], b0);
            b1 = dot2(wxi[4 * c + 1], xu.h[1], b1);
            b2 = dot2(wxi[4 * c + 2], xu.h[2], b2);
            b3 = dot2(wxi[4 * c + 3], xu.h[3], b3);
        }
#pragma unroll
        for (int c = 0; c < 16; ++c) {
            F4H hu; hu.f4 = hi4[c];
            b0 = dot2(whi[4 * c + 0], hu.h[0], b0);
            b1 = dot2(whi[4 * c + 1], hu.h[1], b1);
            b2 = dot2(whi[4 * c + 2], hu.h[2], b2);
            b3 = dot2(whi[4 * c + 3], hu.h[3], b3);
        }
        float acc2 = ((b0 + b1) + (b2 + b3)) + bi2;

        float ap2 = isT ? 2.f * acc2 : acc2;
        float s2  = __builtin_amdgcn_rcpf(1.f + __expf(-ap2));
        float av2 = isT ? fmaf(2.f, s2, -1.f) : s2;

        // state update inside the quad (no LDS, no barrier)
        float ii = qb<0>(av2), fi = qb<1>(av2), oi = qb<2>(av2), gg = qb<3>(av2);
        float cn_new = fmaf(fi, cn_reg, ii * gg);
        cn_reg = cn_new;
        float c_new = oi * tanh_f(cn_new);
        c_reg = c_new;
        float h_new = o_outer * tanh_f(c_new);

        float hn_n = rolN<4>(h_new);
        if ((j & 7) == 0) hb[u >> 1] = pack2(h_new, hn_n);
        // stash prefetched tile into the other buffer (last read pre-B_a)
        if (stl == 0) xt[tb ^ 1][xtl][xm] = pack2(pr0, pr1);
        barrier_lds();   // B_b: h_t (+ new tile) visible
    }

    // ---- final projection: out[S-1] from h_{S-1} ----
    {
        float p0 = 0.f, p1 = 0.f;
        F4H hu0; hu0.f4 = hb4[2 * ps];
        F4H hu1; hu1.f4 = hb4[2 * ps + 1];
        p0 = dot2(wl[0].h[0], hu0.h[0], p0);
        p1 = dot2(wl[0].h[1], hu0.h[1], p1);
        p0 = dot2(wl[0].h[2], hu0.h[2], p0);
        p1 = dot2(wl[0].h[3], hu0.h[3], p1);
        p0 = dot2(wl[1].h[0], hu1.h[0], p0);
        p1 = dot2(wl[1].h[1], hu1.h[1], p1);
        p0 = dot2(wl[1].h[2], hu1.h[2], p0);
        p1 = dot2(wl[1].h[3], hu1.h[3], p1);
        float p = p0 + p1;
        p += rolN<4>(p);
        p += rolN<2>(p);
        p += rolN<1>(p);
        if (ps == 0) orow[(size_t)(SS - 1) * OO + pn] = p + bl;
    }
}

extern "C" void kernel_launch(void* const* d_in, const int* in_sizes, int n_in,
                              void* d_out, int out_size, void* d_ws, size_t ws_size,
                              hipStream_t stream) {
    (void)in_sizes; (void)n_in; (void)d_ws; (void)ws_size; (void)out_size;
    const float* x      = (const float*)d_in[0];
    const float* Wx_out = (const float*)d_in[1];
    const float* Wh_out = (const float*)d_in[2];
    const float* b_out  = (const float*)d_in[3];
    const float* Wx_in  = (const float*)d_in[4];
    const float* Wh_in  = (const float*)d_in[5];
    const float* b_in   = (const float*)d_in[6];
    const float* W_lin  = (const float*)d_in[7];
    const float* b_lin  = (const float*)d_in[8];
    float* out = (float*)d_out;

    nlstm_scan<<<dim3(BB), dim3(512), 0, stream>>>(
        x, Wx_out, Wh_out, b_out, Wx_in, Wh_in, b_in, W_lin, b_lin, out);
}